// Round 1
// baseline (1381.432 us; speedup 1.0000x reference)
//
#include <hip/hip_runtime.h>
#include <math.h>

#define BB 4
#define SS 2048
#define DD 1024
#define HH 16
#define HDD 64
#define NN (BB*SS)            // 8192 rows
#define WINDOWF 604800.0f     // 7 days
#define SCALEF 0.125f         // 1/sqrt(64)

// ---------------------------------------------------------------------------
// GEMM: Y = (X @ W^T + bias) * alpha
// X[nr,kd] row-major, W[nc,kd] row-major (torch Linear weight), Y[nr,nc]
// 128x128 tile, BK=16, 256 threads, 8x8 microtile.
// ---------------------------------------------------------------------------
template<int BM, int BN, int BK>
__global__ __launch_bounds__(256)
void gemm_xwt(const float* __restrict__ X, const float* __restrict__ W,
              const float* __restrict__ bias, float* __restrict__ Y,
              int nr, int nc, int kd, float alpha)
{
    __shared__ float As[BK][BM + 4];
    __shared__ float Bs[BK][BN + 4];
    const int bm = blockIdx.x * BM;
    const int bn = blockIdx.y * BN;
    const int tid = threadIdx.x;
    const int ty = tid >> 4, tx = tid & 15;

    float acc[8][8];
#pragma unroll
    for (int i = 0; i < 8; ++i)
#pragma unroll
        for (int j = 0; j < 8; ++j) acc[i][j] = 0.f;

    for (int k0 = 0; k0 < kd; k0 += BK) {
#pragma unroll
        for (int it = 0; it < (BM * BK) / (256 * 4); ++it) {
            int idx = (it * 256 + tid) * 4;
            int r = idx / BK, c = idx % BK;
            const float4 v = *(const float4*)(X + (size_t)(bm + r) * kd + k0 + c);
            As[c + 0][r] = v.x; As[c + 1][r] = v.y; As[c + 2][r] = v.z; As[c + 3][r] = v.w;
        }
#pragma unroll
        for (int it = 0; it < (BN * BK) / (256 * 4); ++it) {
            int idx = (it * 256 + tid) * 4;
            int r = idx / BK, c = idx % BK;
            const float4 v = *(const float4*)(W + (size_t)(bn + r) * kd + k0 + c);
            Bs[c + 0][r] = v.x; Bs[c + 1][r] = v.y; Bs[c + 2][r] = v.z; Bs[c + 3][r] = v.w;
        }
        __syncthreads();
#pragma unroll
        for (int kk = 0; kk < BK; ++kk) {
            float a[8], b[8];
            *(float4*)&a[0] = *(const float4*)&As[kk][ty * 8];
            *(float4*)&a[4] = *(const float4*)&As[kk][ty * 8 + 4];
            *(float4*)&b[0] = *(const float4*)&Bs[kk][tx * 8];
            *(float4*)&b[4] = *(const float4*)&Bs[kk][tx * 8 + 4];
#pragma unroll
            for (int i = 0; i < 8; ++i)
#pragma unroll
                for (int j = 0; j < 8; ++j)
                    acc[i][j] = fmaf(a[i], b[j], acc[i][j]);
        }
        __syncthreads();
    }

    float bv_[8];
#pragma unroll
    for (int j = 0; j < 8; ++j) bv_[j] = bias[bn + tx * 8 + j];

#pragma unroll
    for (int i = 0; i < 8; ++i) {
        const size_t row = (size_t)(bm + ty * 8 + i);
        float* yrow = Y + row * nc + bn + tx * 8;
        float4 o0, o1;
        o0.x = (acc[i][0] + bv_[0]) * alpha;
        o0.y = (acc[i][1] + bv_[1]) * alpha;
        o0.z = (acc[i][2] + bv_[2]) * alpha;
        o0.w = (acc[i][3] + bv_[3]) * alpha;
        o1.x = (acc[i][4] + bv_[4]) * alpha;
        o1.y = (acc[i][5] + bv_[5]) * alpha;
        o1.z = (acc[i][6] + bv_[6]) * alpha;
        o1.w = (acc[i][7] + bv_[7]) * alpha;
        *(float4*)(yrow + 0) = o0;
        *(float4*)(yrow + 4) = o1;
    }
}

// ---------------------------------------------------------------------------
// Per-query band bounds via binary search (timestamps sorted per sequence).
// Conservative by +/-1s slack; exact f32 mask applied inside attention tile.
// ---------------------------------------------------------------------------
__global__ __launch_bounds__(256)
void band_bounds(const float* __restrict__ ts, int* __restrict__ lo, int* __restrict__ hi)
{
    int idx = blockIdx.x * 256 + threadIdx.x;
    if (idx >= NN) return;
    int b = idx / SS, q = idx % SS;
    const float* t = ts + (size_t)b * SS;
    float tq = t[q];
    float lot = tq - WINDOWF - 1.0f;
    float hit = tq + WINDOWF + 1.0f;
    // first k with t[k] >= lot, search [0, q]
    int l = 0, r = q;
    while (l < r) { int m = (l + r) >> 1; if (t[m] < lot) l = m + 1; else r = m; }
    lo[idx] = l;
    // last k with t[k] <= hit, search [q, S-1]
    int l2 = q, r2 = SS - 1;
    while (l2 < r2) { int m = (l2 + r2 + 1) >> 1; if (t[m] > hit) r2 = m - 1; else l2 = m; }
    hi[idx] = l2;
}

// ---------------------------------------------------------------------------
// Flash attention with time-band mask. One block per (b, h, 64-query tile).
// Q pre-scaled by 1/sqrt(HD). 256 threads, 16x16 grid, 4x4 microtile.
// LDS: Qs[64][68], KP[64][68] (K^T during QK, then P), Vs[64][68].
// ---------------------------------------------------------------------------
__global__ __launch_bounds__(256)
void attn_kernel(const float* __restrict__ Qg, const float* __restrict__ Kg,
                 const float* __restrict__ Vg, const float* __restrict__ Tg,
                 const int* __restrict__ lo, const int* __restrict__ hi,
                 float* __restrict__ Att)
{
    __shared__ float Qs[64][HDD + 4];
    __shared__ float KP[64][64 + 4];   // K^T ([d][k]) during QK; P ([q][k]) after
    __shared__ float Vs[64][HDD + 4];
    __shared__ float tqs[64];
    __shared__ float tks[64];

    const int blk = blockIdx.x;
    const int qt = blk & 31;            // S/64 = 32
    const int h  = (blk >> 5) & 15;
    const int b  = blk >> 9;
    const int q0 = qt * 64;
    const int tid = threadIdx.x;
    const int ty = tid >> 4, tx = tid & 15;

    // load Q tile (already scaled) + query timestamps
#pragma unroll
    for (int p = 0; p < 4; ++p) {
        int r = p * 16 + (tid >> 4);
        int c = (tid & 15) * 4;
        float4 v = *(const float4*)(Qg + ((size_t)(b * SS + q0 + r)) * DD + h * HDD + c);
        *(float4*)&Qs[r][c] = v;
    }
    if (tid < 64) tqs[tid] = Tg[(size_t)b * SS + q0 + tid];

    float m[4], l[4], o[4][4];
#pragma unroll
    for (int i = 0; i < 4; ++i) {
        m[i] = -1e30f; l[i] = 0.f;
#pragma unroll
        for (int j = 0; j < 4; ++j) o[i][j] = 0.f;
    }

    const int t0 = lo[(size_t)b * SS + q0] >> 6;
    const int t1 = hi[(size_t)b * SS + q0 + 63] >> 6;

    for (int t = t0; t <= t1; ++t) {
        const int kk0 = t * 64;
        __syncthreads();   // prev iteration's PV reads of KP/Vs complete
        // load K tile transposed ([d][k]) and V tile row-major, + key timestamps
#pragma unroll
        for (int p = 0; p < 4; ++p) {
            int r = p * 16 + (tid >> 4);
            int c = (tid & 15) * 4;
            float4 kv = *(const float4*)(Kg + ((size_t)(b * SS + kk0 + r)) * DD + h * HDD + c);
            KP[c + 0][r] = kv.x; KP[c + 1][r] = kv.y; KP[c + 2][r] = kv.z; KP[c + 3][r] = kv.w;
            float4 vv = *(const float4*)(Vg + ((size_t)(b * SS + kk0 + r)) * DD + h * HDD + c);
            *(float4*)&Vs[r][c] = vv;
        }
        if (tid < 64) tks[tid] = Tg[(size_t)b * SS + kk0 + tid];
        __syncthreads();

        // QK^T: s[i][j] = sum_d Qs[ty*4+i][d] * K[tx*4+j][d]
        float s[4][4];
#pragma unroll
        for (int i = 0; i < 4; ++i)
#pragma unroll
            for (int j = 0; j < 4; ++j) s[i][j] = 0.f;

#pragma unroll
        for (int d0 = 0; d0 < HDD; d0 += 4) {
            float qa[4][4], ka[4][4];
#pragma unroll
            for (int i = 0; i < 4; ++i)
                *(float4*)qa[i] = *(const float4*)&Qs[ty * 4 + i][d0];
#pragma unroll
            for (int u = 0; u < 4; ++u)
                *(float4*)ka[u] = *(const float4*)&KP[d0 + u][tx * 4];
#pragma unroll
            for (int i = 0; i < 4; ++i)
#pragma unroll
                for (int u = 0; u < 4; ++u)
#pragma unroll
                    for (int j = 0; j < 4; ++j)
                        s[i][j] = fmaf(qa[i][u], ka[u][j], s[i][j]);
        }

        // mask + online softmax (row state replicated across the 16 tx lanes)
        float pfac[4];
#pragma unroll
        for (int i = 0; i < 4; ++i) {
            float tqi = tqs[ty * 4 + i];
#pragma unroll
            for (int j = 0; j < 4; ++j) {
                float tkj = tks[tx * 4 + j];
                if (!(fabsf(tqi - tkj) <= WINDOWF)) s[i][j] = -INFINITY;
            }
            float mt = fmaxf(fmaxf(s[i][0], s[i][1]), fmaxf(s[i][2], s[i][3]));
            mt = fmaxf(mt, __shfl_xor(mt, 1));
            mt = fmaxf(mt, __shfl_xor(mt, 2));
            mt = fmaxf(mt, __shfl_xor(mt, 4));
            mt = fmaxf(mt, __shfl_xor(mt, 8));
            float mn = fmaxf(m[i], mt);
            float f = __expf(m[i] - mn);
            float rs = 0.f;
#pragma unroll
            for (int j = 0; j < 4; ++j) {
                float p = __expf(s[i][j] - mn);
                s[i][j] = p;
                rs += p;
            }
            rs += __shfl_xor(rs, 1);
            rs += __shfl_xor(rs, 2);
            rs += __shfl_xor(rs, 4);
            rs += __shfl_xor(rs, 8);
            l[i] = l[i] * f + rs;
            m[i] = mn;
            pfac[i] = f;
#pragma unroll
            for (int j = 0; j < 4; ++j) o[i][j] *= f;
        }
        (void)pfac;

        __syncthreads();   // all QK reads of KP done; reuse as P
#pragma unroll
        for (int i = 0; i < 4; ++i) {
            float4 pv;
            pv.x = s[i][0]; pv.y = s[i][1]; pv.z = s[i][2]; pv.w = s[i][3];
            *(float4*)&KP[ty * 4 + i][tx * 4] = pv;
        }
        __syncthreads();

        // PV: o[i][j] += sum_k P[ty*4+i][k] * V[k][tx*4+j]
#pragma unroll
        for (int j0 = 0; j0 < 64; j0 += 4) {
            float pa[4][4], va[4][4];
#pragma unroll
            for (int i = 0; i < 4; ++i)
                *(float4*)pa[i] = *(const float4*)&KP[ty * 4 + i][j0];
#pragma unroll
            for (int u = 0; u < 4; ++u)
                *(float4*)va[u] = *(const float4*)&Vs[j0 + u][tx * 4];
#pragma unroll
            for (int i = 0; i < 4; ++i)
#pragma unroll
                for (int u = 0; u < 4; ++u)
#pragma unroll
                    for (int j = 0; j < 4; ++j)
                        o[i][j] = fmaf(pa[i][u], va[u][j], o[i][j]);
        }
    }

    // finalize: divide by l, store to attended [B,S,H,HD]
#pragma unroll
    for (int i = 0; i < 4; ++i) {
        float inv = 1.f / l[i];
        float4 ov;
        ov.x = o[i][0] * inv; ov.y = o[i][1] * inv;
        ov.z = o[i][2] * inv; ov.w = o[i][3] * inv;
        *(float4*)(Att + ((size_t)(b * SS + q0 + ty * 4 + i)) * DD + h * HDD + tx * 4) = ov;
    }
}

// ---------------------------------------------------------------------------
// change_scores[n] = out[n,:] . Wc + bc   (one wave per row)
// ---------------------------------------------------------------------------
__global__ __launch_bounds__(256)
void change_kernel(const float* __restrict__ out, const float* __restrict__ Wc,
                   const float* __restrict__ bc, float* __restrict__ cs)
{
    int row = blockIdx.x * 4 + (threadIdx.x >> 6);
    int lane = threadIdx.x & 63;
    const float* o = out + (size_t)row * DD;
    float sum = 0.f;
#pragma unroll
    for (int k = 0; k < DD / 256; ++k) {
        int c = lane * 4 + k * 256;
        float4 v = *(const float4*)(o + c);
        float4 w = *(const float4*)(Wc + c);
        sum += v.x * w.x + v.y * w.y + v.z * w.z + v.w * w.w;
    }
#pragma unroll
    for (int off = 1; off < 64; off <<= 1) sum += __shfl_xor(sum, off);
    if (lane == 0) cs[row] = sum + bc[0];
}

// ---------------------------------------------------------------------------
extern "C" void kernel_launch(void* const* d_in, const int* in_sizes, int n_in,
                              void* d_out, int out_size, void* d_ws, size_t ws_size,
                              hipStream_t stream)
{
    (void)in_sizes; (void)n_in; (void)out_size; (void)ws_size;
    const float* x  = (const float*)d_in[0];
    const float* ts = (const float*)d_in[1];
    const float* Wq = (const float*)d_in[2];
    const float* bq = (const float*)d_in[3];
    const float* Wk = (const float*)d_in[4];
    const float* bk = (const float*)d_in[5];
    const float* Wv = (const float*)d_in[6];
    const float* bv = (const float*)d_in[7];
    const float* Wo = (const float*)d_in[8];
    const float* bo = (const float*)d_in[9];
    const float* Wc = (const float*)d_in[10];
    const float* bc = (const float*)d_in[11];

    float* out = (float*)d_out;                 // [N*D] output, then [N] change scores
    float* Qb = (float*)d_ws;
    float* Kb = Qb + (size_t)NN * DD;
    float* Vb = Kb + (size_t)NN * DD;
    float* Ab = Vb + (size_t)NN * DD;
    int*   lo = (int*)(Ab + (size_t)NN * DD);
    int*   hi = lo + NN;

    dim3 g(NN / 128, DD / 128);
    gemm_xwt<128, 128, 16><<<g, 256, 0, stream>>>(x, Wq, bq, Qb, NN, DD, DD, SCALEF);
    gemm_xwt<128, 128, 16><<<g, 256, 0, stream>>>(x, Wk, bk, Kb, NN, DD, DD, 1.0f);
    gemm_xwt<128, 128, 16><<<g, 256, 0, stream>>>(x, Wv, bv, Vb, NN, DD, DD, 1.0f);
    band_bounds<<<NN / 256, 256, 0, stream>>>(ts, lo, hi);
    attn_kernel<<<BB * HH * (SS / 64), 256, 0, stream>>>(Qb, Kb, Vb, ts, lo, hi, Ab);
    gemm_xwt<128, 128, 16><<<g, 256, 0, stream>>>(Ab, Wo, bo, out, NN, DD, DD, 1.0f);
    change_kernel<<<NN / 4, 256, 0, stream>>>(out, Wc, bc, out + (size_t)NN * DD);
}

// Round 2
// 309.048 us; speedup vs baseline: 4.4700x; 4.4700x over previous
//
#include <hip/hip_runtime.h>
#include <math.h>

#define BB 4
#define SS 2048
#define DD 1024
#define HH 16
#define HDD 64
#define NN (BB*SS)            // 8192 rows
#define WINDOWF 604800.0f     // 7 days
#define SCALEF 0.125f         // 1/sqrt(64)

typedef __attribute__((ext_vector_type(8))) short bf16x8;
typedef __attribute__((ext_vector_type(4))) short s16x4;
typedef __attribute__((ext_vector_type(4))) float f32x4;

__device__ __forceinline__ unsigned short f2b(float f) {
    unsigned int x = __float_as_uint(f);
    unsigned int r = x + 0x7FFFu + ((x >> 16) & 1u);
    return (unsigned short)(r >> 16);
}

// ---------------------------------------------------------------------------
// f32 -> bf16 (RTN), vectorized
// ---------------------------------------------------------------------------
__global__ __launch_bounds__(256)
void cvt_bf16(const float* __restrict__ src, unsigned short* __restrict__ dst, int n)
{
    int i = (blockIdx.x * 256 + threadIdx.x) * 4;
    if (i >= n) return;
    float4 v = *(const float4*)(src + i);
    s16x4 o;
    o[0] = (short)f2b(v.x); o[1] = (short)f2b(v.y);
    o[2] = (short)f2b(v.z); o[3] = (short)f2b(v.w);
    *(s16x4*)(dst + i) = o;
}

// ---------------------------------------------------------------------------
// bf16 MFMA GEMM: Y = (A @ Bw^T + bias) * alpha
// A[M][K] bf16 row-major, Bw[N][K] bf16 row-major (torch Linear weight layout)
// 128x128 tile, BK=32, 256 threads = 4 waves, each wave 64x64 via 4x4
// mfma_f32_16x16x32_bf16 fragments. LDS rows padded to 40 elems (80 B) so
// ds_read_b128 phase groups cover all 32 banks (conflict-free).
// OUTBF=1 -> bf16 output, OUTBF=0 -> f32 output.
// ---------------------------------------------------------------------------
template<int OUTBF>
__global__ __launch_bounds__(256)
void gemm_bf16(const unsigned short* __restrict__ A,
               const unsigned short* __restrict__ Bw,
               const float* __restrict__ bias,
               void* __restrict__ Y, int M, int N, int K, float alpha)
{
    constexpr int BM = 128, BN = 128, BK = 32;
    constexpr int LDA = 40;                       // padded row, elems
    __shared__ unsigned short As[BM * LDA];
    __shared__ unsigned short Bs[BN * LDA];

    const int bm = blockIdx.x * BM;
    const int bn = blockIdx.y * BN;
    const int tid = threadIdx.x;
    const int wid = tid >> 6, l = tid & 63;
    const int wm = (wid >> 1) * 64, wn = (wid & 1) * 64;
    const int lr = l & 15, lg = l >> 4;

    f32x4 acc[4][4];
#pragma unroll
    for (int i = 0; i < 4; ++i)
#pragma unroll
        for (int j = 0; j < 4; ++j) acc[i][j] = (f32x4){0.f, 0.f, 0.f, 0.f};

    for (int k0 = 0; k0 < K; k0 += BK) {
        bf16x8 av[2], bv[2];
#pragma unroll
        for (int t = 0; t < 2; ++t) {
            int idx = t * 256 + tid;
            int r = idx >> 2, c = (idx & 3) * 8;
            av[t] = *(const bf16x8*)(A  + (size_t)(bm + r) * K + k0 + c);
            bv[t] = *(const bf16x8*)(Bw + (size_t)(bn + r) * K + k0 + c);
        }
        __syncthreads();                      // prior compute's LDS reads done
#pragma unroll
        for (int t = 0; t < 2; ++t) {
            int idx = t * 256 + tid;
            int r = idx >> 2, c = (idx & 3) * 8;
            *(bf16x8*)&As[r * LDA + c] = av[t];
            *(bf16x8*)&Bs[r * LDA + c] = bv[t];
        }
        __syncthreads();

        bf16x8 af[4], bf[4];
#pragma unroll
        for (int am = 0; am < 4; ++am)
            af[am] = *(const bf16x8*)&As[(wm + am * 16 + lr) * LDA + lg * 8];
#pragma unroll
        for (int nf = 0; nf < 4; ++nf)
            bf[nf] = *(const bf16x8*)&Bs[(wn + nf * 16 + lr) * LDA + lg * 8];
#pragma unroll
        for (int am = 0; am < 4; ++am)
#pragma unroll
            for (int nf = 0; nf < 4; ++nf)
                acc[am][nf] = __builtin_amdgcn_mfma_f32_16x16x32_bf16(
                    af[am], bf[nf], acc[am][nf], 0, 0, 0);
    }

    float bia[4];
#pragma unroll
    for (int nf = 0; nf < 4; ++nf) bia[nf] = bias[bn + wn + nf * 16 + lr];

#pragma unroll
    for (int am = 0; am < 4; ++am)
#pragma unroll
        for (int nf = 0; nf < 4; ++nf)
#pragma unroll
            for (int r = 0; r < 4; ++r) {
                float o = (acc[am][nf][r] + bia[nf]) * alpha;
                size_t m = (size_t)(bm + wm + am * 16 + lg * 4 + r);
                size_t n = (size_t)(bn + wn + nf * 16 + lr);
                if (OUTBF) ((unsigned short*)Y)[m * N + n] = f2b(o);
                else       ((float*)Y)[m * N + n] = o;
            }
}

// ---------------------------------------------------------------------------
// Per-query band bounds via binary search (timestamps sorted per sequence).
// ---------------------------------------------------------------------------
__global__ __launch_bounds__(256)
void band_bounds(const float* __restrict__ ts, int* __restrict__ lo, int* __restrict__ hi)
{
    int idx = blockIdx.x * 256 + threadIdx.x;
    if (idx >= NN) return;
    int b = idx / SS, q = idx % SS;
    const float* t = ts + (size_t)b * SS;
    float tq = t[q];
    float lot = tq - WINDOWF - 1.0f;
    float hit = tq + WINDOWF + 1.0f;
    int l = 0, r = q;
    while (l < r) { int m = (l + r) >> 1; if (t[m] < lot) l = m + 1; else r = m; }
    lo[idx] = l;
    int l2 = q, r2 = SS - 1;
    while (l2 < r2) { int m = (l2 + r2 + 1) >> 1; if (t[m] > hit) r2 = m - 1; else l2 = m; }
    hi[idx] = l2;
}

// ---------------------------------------------------------------------------
// MFMA flash attention with time-band mask.
// Block = 256 thr (4 waves) per (b, h, 64-query tile). Wave w owns 16 q-rows.
// QK^T: Q/K bf16x8 fragments straight from global (L2-resident).
// P staged in padded LDS; V staged transposed in XOR-swizzled LDS.
// Online softmax in registers (rows live in C-layout lanes).
// ---------------------------------------------------------------------------
__global__ __launch_bounds__(256)
void attn_mfma(const unsigned short* __restrict__ Qb, const unsigned short* __restrict__ Kb,
               const unsigned short* __restrict__ Vb, const float* __restrict__ Tg,
               const int* __restrict__ lo, const int* __restrict__ hi,
               unsigned short* __restrict__ Ab)
{
    constexpr int VTS = 72;                       // padded row, elems
    __shared__ unsigned short Vt[64 * VTS];       // [d][k] xor-swizzled
    __shared__ unsigned short Pl[64 * VTS];       // [q][k]

    const int blk = blockIdx.x;
    const int qt = blk & 31, h = (blk >> 5) & 15, b = blk >> 9;
    const int q0 = qt * 64;
    const int tid = threadIdx.x;
    const int wid = tid >> 6, l = tid & 63;
    const int lr = l & 15, lg = l >> 4;

    // Q fragments for this wave's 16-row strip (d = 0..31, 32..63)
    const size_t qrow = (size_t)(b * SS + q0 + wid * 16 + lr);
    bf16x8 qf0 = *(const bf16x8*)(Qb + qrow * DD + h * HDD + lg * 8);
    bf16x8 qf1 = *(const bf16x8*)(Qb + qrow * DD + h * HDD + 32 + lg * 8);

    float tqv[4];
#pragma unroll
    for (int r = 0; r < 4; ++r)
        tqv[r] = Tg[(size_t)b * SS + q0 + wid * 16 + lg * 4 + r];

    float m_[4], l_[4];
    f32x4 oacc[4];
#pragma unroll
    for (int r = 0; r < 4; ++r) { m_[r] = -1e30f; l_[r] = 0.f; }
#pragma unroll
    for (int df = 0; df < 4; ++df) oacc[df] = (f32x4){0.f, 0.f, 0.f, 0.f};

    const int t0 = lo[(size_t)b * SS + q0] >> 6;
    const int t1 = hi[(size_t)b * SS + q0 + 63] >> 6;

    for (int t = t0; t <= t1; ++t) {
        const int kk0 = t * 64;

        // V tile -> regs (coalesced), then transposed+swizzled into LDS
        bf16x8 vv[2]; int vr[2], vc[2];
#pragma unroll
        for (int it = 0; it < 2; ++it) {
            int idx = it * 256 + tid;
            vr[it] = idx >> 3; vc[it] = (idx & 7) * 8;
            vv[it] = *(const bf16x8*)(Vb + (size_t)(b * SS + kk0 + vr[it]) * DD + h * HDD + vc[it]);
        }
        __syncthreads();                          // prev tile's Pl/Vt reads done
#pragma unroll
        for (int it = 0; it < 2; ++it)
#pragma unroll
            for (int j = 0; j < 8; ++j) {
                int d = vc[it] + j;
                Vt[d * VTS + (vr[it] ^ (((d >> 3) & 7) << 3))] = (unsigned short)vv[it][j];
            }

        float tkv[4];
#pragma unroll
        for (int kf = 0; kf < 4; ++kf)
            tkv[kf] = Tg[(size_t)b * SS + kk0 + kf * 16 + lr];

        // QK^T: 4 col-fragments of 16 keys, contraction over d=64 in 2 MFMAs
        f32x4 s[4];
#pragma unroll
        for (int kf = 0; kf < 4; ++kf) {
            const size_t krow = (size_t)(b * SS + kk0 + kf * 16 + lr);
            bf16x8 kf0 = *(const bf16x8*)(Kb + krow * DD + h * HDD + lg * 8);
            bf16x8 kf1 = *(const bf16x8*)(Kb + krow * DD + h * HDD + 32 + lg * 8);
            f32x4 z = (f32x4){0.f, 0.f, 0.f, 0.f};
            z = __builtin_amdgcn_mfma_f32_16x16x32_bf16(qf0, kf0, z, 0, 0, 0);
            z = __builtin_amdgcn_mfma_f32_16x16x32_bf16(qf1, kf1, z, 0, 0, 0);
            s[kf] = z;
        }

        // exact time-window mask
#pragma unroll
        for (int kf = 0; kf < 4; ++kf)
#pragma unroll
            for (int r = 0; r < 4; ++r)
                if (!(fabsf(tqv[r] - tkv[kf]) <= WINDOWF)) s[kf][r] = -INFINITY;

        // online softmax update (row r state replicated across 16 lanes)
        float f_[4], rs[4];
#pragma unroll
        for (int r = 0; r < 4; ++r) {
            float mt = fmaxf(fmaxf(s[0][r], s[1][r]), fmaxf(s[2][r], s[3][r]));
            mt = fmaxf(mt, __shfl_xor(mt, 1));
            mt = fmaxf(mt, __shfl_xor(mt, 2));
            mt = fmaxf(mt, __shfl_xor(mt, 4));
            mt = fmaxf(mt, __shfl_xor(mt, 8));
            float mn = fmaxf(m_[r], mt);
            f_[r] = __expf(m_[r] - mn);
            float acc_s = 0.f;
#pragma unroll
            for (int kf = 0; kf < 4; ++kf) {
                float p = __expf(s[kf][r] - mn);
                s[kf][r] = p;
                acc_s += p;
            }
            acc_s += __shfl_xor(acc_s, 1);
            acc_s += __shfl_xor(acc_s, 2);
            acc_s += __shfl_xor(acc_s, 4);
            acc_s += __shfl_xor(acc_s, 8);
            rs[r] = acc_s;
            l_[r] = l_[r] * f_[r] + rs[r];
            m_[r] = mn;
        }
#pragma unroll
        for (int df = 0; df < 4; ++df)
#pragma unroll
            for (int r = 0; r < 4; ++r) oacc[df][r] *= f_[r];

        // P -> LDS bf16
#pragma unroll
        for (int kf = 0; kf < 4; ++kf)
#pragma unroll
            for (int r = 0; r < 4; ++r)
                Pl[(wid * 16 + lg * 4 + r) * VTS + kf * 16 + lr] = f2b(s[kf][r]);
        __syncthreads();                          // Vt + Pl visible

        // PV: contraction over 64 keys in 2 halves
#pragma unroll
        for (int kh = 0; kh < 2; ++kh) {
            bf16x8 pf = *(const bf16x8*)&Pl[(wid * 16 + lr) * VTS + kh * 32 + lg * 8];
#pragma unroll
            for (int df = 0; df < 4; ++df) {
                int d = df * 16 + lr;
                int kb = (kh * 32 + lg * 8) ^ (((d >> 3) & 7) << 3);
                bf16x8 vf = *(const bf16x8*)&Vt[d * VTS + kb];
                oacc[df] = __builtin_amdgcn_mfma_f32_16x16x32_bf16(pf, vf, oacc[df], 0, 0, 0);
            }
        }
    }

    // finalize: attended = oacc / l, store bf16
#pragma unroll
    for (int r = 0; r < 4; ++r) l_[r] = 1.f / l_[r];
#pragma unroll
    for (int df = 0; df < 4; ++df)
#pragma unroll
        for (int r = 0; r < 4; ++r) {
            size_t row = (size_t)(b * SS + q0 + wid * 16 + lg * 4 + r);
            Ab[row * DD + h * HDD + df * 16 + lr] = f2b(oacc[df][r] * l_[r]);
        }
}

// ---------------------------------------------------------------------------
// change_scores[n] = out[n,:] . Wc + bc   (one wave per row)
// ---------------------------------------------------------------------------
__global__ __launch_bounds__(256)
void change_kernel(const float* __restrict__ out, const float* __restrict__ Wc,
                   const float* __restrict__ bc, float* __restrict__ cs)
{
    int row = blockIdx.x * 4 + (threadIdx.x >> 6);
    int lane = threadIdx.x & 63;
    const float* o = out + (size_t)row * DD;
    float sum = 0.f;
#pragma unroll
    for (int k = 0; k < DD / 256; ++k) {
        int c = lane * 4 + k * 256;
        float4 v = *(const float4*)(o + c);
        float4 w = *(const float4*)(Wc + c);
        sum += v.x * w.x + v.y * w.y + v.z * w.z + v.w * w.w;
    }
#pragma unroll
    for (int off = 1; off < 64; off <<= 1) sum += __shfl_xor(sum, off);
    if (lane == 0) cs[row] = sum + bc[0];
}

// ---------------------------------------------------------------------------
extern "C" void kernel_launch(void* const* d_in, const int* in_sizes, int n_in,
                              void* d_out, int out_size, void* d_ws, size_t ws_size,
                              hipStream_t stream)
{
    (void)in_sizes; (void)n_in; (void)out_size; (void)ws_size;
    const float* x  = (const float*)d_in[0];
    const float* ts = (const float*)d_in[1];
    const float* Wq = (const float*)d_in[2];
    const float* bq = (const float*)d_in[3];
    const float* Wk = (const float*)d_in[4];
    const float* bk = (const float*)d_in[5];
    const float* Wv = (const float*)d_in[6];
    const float* bv = (const float*)d_in[7];
    const float* Wo = (const float*)d_in[8];
    const float* bo = (const float*)d_in[9];
    const float* Wc = (const float*)d_in[10];
    const float* bc = (const float*)d_in[11];

    float* out = (float*)d_out;                 // [N*D] output, then [N] change scores

    unsigned short* xb  = (unsigned short*)d_ws;
    unsigned short* Qb  = xb  + (size_t)NN * DD;
    unsigned short* Kb2 = Qb  + (size_t)NN * DD;
    unsigned short* Vb2 = Kb2 + (size_t)NN * DD;
    unsigned short* Abf = Vb2 + (size_t)NN * DD;
    unsigned short* Wqb = Abf + (size_t)NN * DD;
    unsigned short* Wkb = Wqb + (size_t)DD * DD;
    unsigned short* Wvb = Wkb + (size_t)DD * DD;
    unsigned short* Wob = Wvb + (size_t)DD * DD;
    int* lo = (int*)(Wob + (size_t)DD * DD);
    int* hi = lo + NN;

    // converts
    cvt_bf16<<<(NN * DD / 4 + 255) / 256, 256, 0, stream>>>(x, xb, NN * DD);
    cvt_bf16<<<(DD * DD / 4 + 255) / 256, 256, 0, stream>>>(Wq, Wqb, DD * DD);
    cvt_bf16<<<(DD * DD / 4 + 255) / 256, 256, 0, stream>>>(Wk, Wkb, DD * DD);
    cvt_bf16<<<(DD * DD / 4 + 255) / 256, 256, 0, stream>>>(Wv, Wvb, DD * DD);
    cvt_bf16<<<(DD * DD / 4 + 255) / 256, 256, 0, stream>>>(Wo, Wob, DD * DD);

    dim3 g(NN / 128, DD / 128);
    gemm_bf16<1><<<g, 256, 0, stream>>>(xb, Wqb, bq, Qb,  NN, DD, DD, SCALEF);
    gemm_bf16<1><<<g, 256, 0, stream>>>(xb, Wkb, bk, Kb2, NN, DD, DD, 1.0f);
    gemm_bf16<1><<<g, 256, 0, stream>>>(xb, Wvb, bv, Vb2, NN, DD, DD, 1.0f);
    band_bounds<<<NN / 256, 256, 0, stream>>>(ts, lo, hi);
    attn_mfma<<<BB * HH * (SS / 64), 256, 0, stream>>>(Qb, Kb2, Vb2, ts, lo, hi, Abf);
    gemm_bf16<0><<<g, 256, 0, stream>>>(Abf, Wob, bo, out, NN, DD, DD, 1.0f);
    change_kernel<<<NN / 4, 256, 0, stream>>>(out, Wc, bc, out + (size_t)NN * DD);
}